// Round 4
// baseline (320.825 us; speedup 1.0000x reference)
//
#include <hip/hip_runtime.h>
#include <math.h>

// Problem constants (fixed by reference)
#define BB 32     // batch
#define CC 512    // channels
#define CQ 64     // qk channels
#define NN 1024   // Nq = Nk = 32*32

typedef __attribute__((ext_vector_type(8))) short short8;   // 8 bf16 = 4 VGPR
typedef __attribute__((ext_vector_type(4))) float f32x4;    // MFMA C/D frag

#define MFMA16(a, b, c) __builtin_amdgcn_mfma_f32_16x16x32_bf16(a, b, c, 0, 0, 0)

// P/Z LDS row stride in ushorts: 512 + 8 pad -> 1040 B (16B aligned).
// 16-row x 4-kslot b128 reads spread uniformly over all 32 banks (8-cyc min).
#define PSTR 520

__device__ __forceinline__ ushort f2bf(float f) {
    uint u = __builtin_bit_cast(uint, f);
    return (ushort)((u + 0x7FFFu + ((u >> 16) & 1u)) >> 16);  // RNE
}

// ---------------------------------------------------------------------------
// All three weight tensors f32 -> bf16 in one launch. grid 320 x 256 exact.
// ---------------------------------------------------------------------------
__global__ __launch_bounds__(256) void k_cvt3(const float* __restrict__ Wq,
                                              const float* __restrict__ Wk,
                                              const float* __restrict__ Wv,
                                              ushort* __restrict__ Wqb,
                                              ushort* __restrict__ Wkb,
                                              ushort* __restrict__ Wvb) {
    int i = blockIdx.x * 256 + threadIdx.x;  // f4 index over 81920
    const float* src;
    ushort* dst;
    int off;
    if (i < 8192) { src = Wq; dst = Wqb; off = i; }
    else if (i < 16384) { src = Wk; dst = Wkb; off = i - 8192; }
    else { src = Wv; dst = Wvb; off = i - 16384; }
    float4 v = reinterpret_cast<const float4*>(src)[off];
    ushort4 o;
    o.x = f2bf(v.x); o.y = f2bf(v.y); o.z = f2bf(v.z); o.w = f2bf(v.w);
    reinterpret_cast<ushort4*>(dst)[off] = o;
}

// ---------------------------------------------------------------------------
// Qt[b][n][cq] = sum_c src[b][c][n]*W[cq][c] + bias[cq]   (bf16 out)
// sel=1 additionally emits audio_b (bf16 copy) from the staged float4 loads.
// grid (16 ntiles, 2 sel, B), block 256 (4 waves). LDS [c][n], transpose at read.
// ---------------------------------------------------------------------------
__global__ __launch_bounds__(256) void k_proj(const float* __restrict__ face,
                                              const float* __restrict__ audio,
                                              const ushort* __restrict__ Wqb,
                                              const float* __restrict__ bq,
                                              const ushort* __restrict__ Wkb,
                                              const float* __restrict__ bk,
                                              ushort* __restrict__ Qt,
                                              ushort* __restrict__ Kt,
                                              ushort* __restrict__ audio_b) {
    const int sel = blockIdx.y;
    const int b = blockIdx.z;
    const int n0 = blockIdx.x * 64;
    const float* src = sel ? audio : face;
    const ushort* Wb = sel ? Wkb : Wqb;
    const float* bias = sel ? bk : bq;
    ushort* dst = sel ? Kt : Qt;

    __shared__ float ldsT[64][65];  // [c][n], pad 1 -> 2-way max (free)
    const int t = threadIdx.x;
    const int w = __builtin_amdgcn_readfirstlane(t >> 6);  // wave 0..3
    const int l15 = t & 15;
    const int l4 = (t & 63) >> 4;

    f32x4 qacc[4];
#pragma unroll
    for (int j = 0; j < 4; ++j) qacc[j] = (f32x4){0.f, 0.f, 0.f, 0.f};

    for (int c0 = 0; c0 < CC; c0 += 64) {
        __syncthreads();
#pragma unroll
        for (int p = 0; p < 4; ++p) {
            int i = t + p * 256;          // 0..1023 float4s
            int c = i >> 4, n4 = (i & 15) * 4;
            float4 v = *reinterpret_cast<const float4*>(
                &src[((size_t)b * CC + c0 + c) * NN + n0 + n4]);
            ldsT[c][n4 + 0] = v.x;
            ldsT[c][n4 + 1] = v.y;
            ldsT[c][n4 + 2] = v.z;
            ldsT[c][n4 + 3] = v.w;
            if (sel) {
                ushort4 u;
                u.x = f2bf(v.x); u.y = f2bf(v.y); u.z = f2bf(v.z); u.w = f2bf(v.w);
                *reinterpret_cast<ushort4*>(
                    &audio_b[((size_t)b * CC + c0 + c) * NN + n0 + n4]) = u;
            }
        }
        __syncthreads();
#pragma unroll
        for (int ksub = 0; ksub < 2; ++ksub) {
            short8 af;
#pragma unroll
            for (int j = 0; j < 8; ++j)
                af[j] = (short)f2bf(ldsT[32 * ksub + 8 * l4 + j][16 * w + l15]);
#pragma unroll
            for (int cqj = 0; cqj < 4; ++cqj) {
                short8 wb = *reinterpret_cast<const short8*>(
                    &Wb[(size_t)(16 * cqj + l15) * CC + c0 + 32 * ksub + 8 * l4]);
                qacc[cqj] = MFMA16(af, wb, qacc[cqj]);
            }
        }
    }
#pragma unroll
    for (int cqj = 0; cqj < 4; ++cqj) {
        float bs = bias[16 * cqj + l15];
#pragma unroll
        for (int reg = 0; reg < 4; ++reg) {
            int n = n0 + 16 * w + 4 * l4 + reg;
            dst[((size_t)b * NN + n) * CQ + 16 * cqj + l15] =
                f2bf(qacc[cqj][reg] + bs);
        }
    }
}

// ---------------------------------------------------------------------------
// Fused attention + output GEMM. One block per (b, 64-n-tile): grid 512,
// block 512 (8 waves), 2 blocks/CU (LDS ~69 KB).
//   S: P[64n][512m] = exp(Qt Kt^T / 8) per strip (2 strips); wave w = 64 m-cols
//   Z: zacc[c][n] += audio[c][m]*P[n][m]; wave (wc=w>>1, wn=w&1) = 128c x 32n
//   O: out = gamma*(Wv . Znorm + bv) + face; Znorm staged in smem as [n][c]
// Wave n-split halves LDS read traffic vs c-only split.
// ---------------------------------------------------------------------------
__global__ __launch_bounds__(512, 4) void k_attn(
    const ushort* __restrict__ Qt, const ushort* __restrict__ Kt,
    const ushort* __restrict__ Ab_, const ushort* __restrict__ Wvb,
    const float* __restrict__ bv, const float* __restrict__ gamma,
    const float* __restrict__ face, float* __restrict__ out) {
    __shared__ ushort smem[64 * PSTR];  // P strip [64n][512m] / Znorm [64n][512c]
    __shared__ float l_acc[8][64];
    __shared__ float linv[64];

    // bijective XCD-chunked swizzle (512 % 8 == 0): 64 consecutive wgs per XCD
    const int wg = blockIdx.x;
    const int swz = (wg & 7) * 64 + (wg >> 3);
    const int b = swz >> 4;
    const int n0 = (swz & 15) * 64;

    const int t = threadIdx.x;
    const int w = __builtin_amdgcn_readfirstlane(t >> 6);  // wave 0..7
    const int l15 = t & 15;
    const int l4 = (t & 63) >> 4;
    const int wc = w >> 1;  // c/o group (128 rows)
    const int wn = w & 1;   // n group (32 cols)

    const ushort* Qb = Qt + ((size_t)b * NN + n0) * CQ;
    const ushort* Kb = Kt + (size_t)b * NN * CQ;
    const ushort* Ab = Ab_ + (size_t)b * CC * NN;

    f32x4 zacc[8][2];  // [ci][nj]: c = 128wc+16ci, n = 32wn+16nj
#pragma unroll
    for (int ci = 0; ci < 8; ++ci)
#pragma unroll
        for (int nj = 0; nj < 2; ++nj) zacc[ci][nj] = (f32x4){0.f, 0.f, 0.f, 0.f};

#pragma unroll 1
    for (int s = 0; s < 2; ++s) {
        const int m0 = s * 512;
        __syncthreads();  // prev strip's Z phase done reading smem
        // ---- S phase: wave w owns m-cols [64w, +64) of this strip
        float lacc[4][4];
#pragma unroll
        for (int ni = 0; ni < 4; ++ni)
#pragma unroll
            for (int r = 0; r < 4; ++r) lacc[ni][r] = 0.f;
#pragma unroll
        for (int mj = 0; mj < 4; ++mj) {
            const ushort* kp = &Kb[(size_t)(m0 + 64 * w + 16 * mj + l15) * CQ + 8 * l4];
            short8 kb0 = *reinterpret_cast<const short8*>(kp);
            short8 kb1 = *reinterpret_cast<const short8*>(kp + 32);
#pragma unroll
            for (int ni = 0; ni < 4; ++ni) {
                const ushort* qp = &Qb[(size_t)(16 * ni + l15) * CQ + 8 * l4];
                short8 qa0 = *reinterpret_cast<const short8*>(qp);
                short8 qa1 = *reinterpret_cast<const short8*>(qp + 32);
                f32x4 sacc = (f32x4){0.f, 0.f, 0.f, 0.f};
                sacc = MFMA16(qa0, kb0, sacc);
                sacc = MFMA16(qa1, kb1, sacc);
#pragma unroll
                for (int r = 0; r < 4; ++r) {
                    float p = exp2f(sacc[r] * 0.18033688011112f);  // exp(S/8)
                    lacc[ni][r] += p;
                    smem[(16 * ni + 4 * l4 + r) * PSTR + 64 * w + 16 * mj + l15] =
                        f2bf(p);
                }
            }
        }
        // partial row-sums over this wave's 64 m-cols (reduce over l15)
#pragma unroll
        for (int ni = 0; ni < 4; ++ni)
#pragma unroll
            for (int r = 0; r < 4; ++r) {
                float v = lacc[ni][r];
                v += __shfl_xor(v, 1, 64);
                v += __shfl_xor(v, 2, 64);
                v += __shfl_xor(v, 4, 64);
                v += __shfl_xor(v, 8, 64);
                if (l15 == 0) {
                    int n = 16 * ni + 4 * l4 + r;
                    l_acc[w][n] = s ? (l_acc[w][n] + v) : v;
                }
            }
        __syncthreads();
        // ---- Z phase: wave (wc, wn): c-rows [128wc,+128), n-cols [32wn,+32)
#pragma unroll 2
        for (int ks = 0; ks < 16; ++ks) {
            short8 af[8];
#pragma unroll
            for (int ci = 0; ci < 8; ++ci)
                af[ci] = *reinterpret_cast<const short8*>(
                    &Ab[(size_t)(128 * wc + 16 * ci + l15) * NN + m0 + 32 * ks + 8 * l4]);
            short8 pb[2];
#pragma unroll
            for (int nj = 0; nj < 2; ++nj)
                pb[nj] = *reinterpret_cast<const short8*>(
                    &smem[(32 * wn + 16 * nj + l15) * PSTR + 32 * ks + 8 * l4]);
#pragma unroll
            for (int ci = 0; ci < 8; ++ci)
#pragma unroll
                for (int nj = 0; nj < 2; ++nj)
                    zacc[ci][nj] = MFMA16(af[ci], pb[nj], zacc[ci][nj]);
        }
    }

    __syncthreads();
    if (t < 64) {
        float ssum = 0.f;
#pragma unroll
        for (int ww = 0; ww < 8; ++ww) ssum += l_acc[ww][t];
        linv[t] = 1.f / ssum;
    }
    __syncthreads();

    // ---- normalize + stage Znorm to smem as [n][c]
    float li[2];
#pragma unroll
    for (int nj = 0; nj < 2; ++nj) li[nj] = linv[32 * wn + 16 * nj + l15];
#pragma unroll
    for (int ci = 0; ci < 8; ++ci)
#pragma unroll
        for (int nj = 0; nj < 2; ++nj) {
            ushort4 o4;
            o4.x = f2bf(zacc[ci][nj][0] * li[nj]);
            o4.y = f2bf(zacc[ci][nj][1] * li[nj]);
            o4.z = f2bf(zacc[ci][nj][2] * li[nj]);
            o4.w = f2bf(zacc[ci][nj][3] * li[nj]);
            *reinterpret_cast<ushort4*>(
                &smem[(32 * wn + 16 * nj + l15) * PSTR + 128 * wc + 16 * ci + 4 * l4]) = o4;
        }
    __syncthreads();

    // ---- O phase: o-rows [128wc,+128), n-cols [32wn,+32); D rows = n (swap!)
    f32x4 facc[8][2];
#pragma unroll
    for (int oi = 0; oi < 8; ++oi)
#pragma unroll
        for (int nj = 0; nj < 2; ++nj) facc[oi][nj] = (f32x4){0.f, 0.f, 0.f, 0.f};
#pragma unroll 2
    for (int ks = 0; ks < 16; ++ks) {
        short8 wa[8];
#pragma unroll
        for (int oi = 0; oi < 8; ++oi)
            wa[oi] = *reinterpret_cast<const short8*>(
                &Wvb[(size_t)(128 * wc + 16 * oi + l15) * CC + 32 * ks + 8 * l4]);
        short8 zb[2];
#pragma unroll
        for (int nj = 0; nj < 2; ++nj)
            zb[nj] = *reinterpret_cast<const short8*>(
                &smem[(32 * wn + 16 * nj + l15) * PSTR + 32 * ks + 8 * l4]);
#pragma unroll
        for (int oi = 0; oi < 8; ++oi)
#pragma unroll
            for (int nj = 0; nj < 2; ++nj)
                facc[oi][nj] = MFMA16(zb[nj], wa[oi], facc[oi][nj]);
    }

    // ---- epilogue: float4 along n (D rows = n via 4l4+reg)
    const float g = gamma[0];
#pragma unroll
    for (int oi = 0; oi < 8; ++oi) {
        int o = 128 * wc + 16 * oi + l15;
        float bvo = bv[o];
#pragma unroll
        for (int nj = 0; nj < 2; ++nj) {
            int n = n0 + 32 * wn + 16 * nj + 4 * l4;
            size_t idx = ((size_t)b * CC + o) * NN + n;
            float4 fc = *reinterpret_cast<const float4*>(&face[idx]);
            float4 ov;
            ov.x = g * (facc[oi][nj][0] + bvo) + fc.x;
            ov.y = g * (facc[oi][nj][1] + bvo) + fc.y;
            ov.z = g * (facc[oi][nj][2] + bvo) + fc.z;
            ov.w = g * (facc[oi][nj][3] + bvo) + fc.w;
            *reinterpret_cast<float4*>(&out[idx]) = ov;
        }
    }
}

// ---------------------------------------------------------------------------
extern "C" void kernel_launch(void* const* d_in, const int* in_sizes, int n_in,
                              void* d_out, int out_size, void* d_ws, size_t ws_size,
                              hipStream_t stream) {
    const float* face  = (const float*)d_in[0];
    const float* audio = (const float*)d_in[1];
    const float* Wq    = (const float*)d_in[2];
    const float* bq    = (const float*)d_in[3];
    const float* Wk    = (const float*)d_in[4];
    const float* bk    = (const float*)d_in[5];
    const float* Wv    = (const float*)d_in[6];
    const float* bv    = (const float*)d_in[7];
    const float* gamma = (const float*)d_in[8];
    float* out = (float*)d_out;
    char* ws = (char*)d_ws;

    // workspace layout (bytes)
    ushort* Qt      = (ushort*)(ws + 0);                       // 4 MB
    ushort* Kt      = (ushort*)(ws + (4u << 20));              // 4 MB
    ushort* audio_b = (ushort*)(ws + (8u << 20));              // 32 MB
    ushort* Wqb     = (ushort*)(ws + (40u << 20));             // 64 KB
    ushort* Wkb     = (ushort*)(ws + (40u << 20) + (64u << 10));
    ushort* Wvb     = (ushort*)(ws + (40u << 20) + (128u << 10));  // 512 KB

    hipLaunchKernelGGL(k_cvt3, dim3(320), dim3(256), 0, stream,
                       Wq, Wk, Wv, Wqb, Wkb, Wvb);
    hipLaunchKernelGGL(k_proj, dim3(16, 2, BB), dim3(256), 0, stream,
                       face, audio, Wqb, bq, Wkb, bk, Qt, Kt, audio_b);
    hipLaunchKernelGGL(k_attn, dim3(512), dim3(512), 0, stream,
                       Qt, Kt, audio_b, Wvb, bv, gamma, face, out);
}

// Round 5
// 284.358 us; speedup vs baseline: 1.1282x; 1.1282x over previous
//
#include <hip/hip_runtime.h>
#include <math.h>

// Problem constants (fixed by reference)
#define BB 32     // batch
#define CC 512    // channels
#define CQ 64     // qk channels
#define NN 1024   // Nq = Nk = 32*32

typedef __attribute__((ext_vector_type(8))) short short8;   // 8 bf16 = 4 VGPR
typedef __attribute__((ext_vector_type(4))) float f32x4;    // MFMA C/D frag

#define MFMA16(a, b, c) __builtin_amdgcn_mfma_f32_16x16x32_bf16(a, b, c, 0, 0, 0)

// P/Z LDS row stride in ushorts: 512 + 8 pad -> 1040 B (16B aligned).
// 16-row x 4-kslot b128 reads spread uniformly over all 32 banks (8-cyc min).
#define PSTR 520

__device__ __forceinline__ ushort f2bf(float f) {
    uint u = __builtin_bit_cast(uint, f);
    return (ushort)((u + 0x7FFFu + ((u >> 16) & 1u)) >> 16);  // RNE
}
__device__ __forceinline__ float bf2f(ushort u) {
    return __builtin_bit_cast(float, ((uint)u) << 16);
}

// ---------------------------------------------------------------------------
// All three weight tensors f32 -> bf16 in one launch. grid 320 x 256 exact.
// ---------------------------------------------------------------------------
__global__ __launch_bounds__(256) void k_cvt3(const float* __restrict__ Wq,
                                              const float* __restrict__ Wk,
                                              const float* __restrict__ Wv,
                                              ushort* __restrict__ Wqb,
                                              ushort* __restrict__ Wkb,
                                              ushort* __restrict__ Wvb) {
    int i = blockIdx.x * 256 + threadIdx.x;  // f4 index over 81920
    const float* src;
    ushort* dst;
    int off;
    if (i < 8192) { src = Wq; dst = Wqb; off = i; }
    else if (i < 16384) { src = Wk; dst = Wkb; off = i - 8192; }
    else { src = Wv; dst = Wvb; off = i - 16384; }
    float4 v = reinterpret_cast<const float4*>(src)[off];
    ushort4 o;
    o.x = f2bf(v.x); o.y = f2bf(v.y); o.z = f2bf(v.z); o.w = f2bf(v.w);
    reinterpret_cast<ushort4*>(dst)[off] = o;
}

// ---------------------------------------------------------------------------
// Qt[b][n][cq] = sum_c src[b][c][n]*W[cq][c] + bias[cq]   (bf16 out)
// sel=1 additionally emits audio_b (bf16 copy) from the staged float4 loads.
// grid (16 ntiles, 2 sel, B), block 256 (4 waves). LDS [c][n], transpose at read.
// ---------------------------------------------------------------------------
__global__ __launch_bounds__(256) void k_proj(const float* __restrict__ face,
                                              const float* __restrict__ audio,
                                              const ushort* __restrict__ Wqb,
                                              const float* __restrict__ bq,
                                              const ushort* __restrict__ Wkb,
                                              const float* __restrict__ bk,
                                              ushort* __restrict__ Qt,
                                              ushort* __restrict__ Kt,
                                              ushort* __restrict__ audio_b) {
    const int sel = blockIdx.y;
    const int b = blockIdx.z;
    const int n0 = blockIdx.x * 64;
    const float* src = sel ? audio : face;
    const ushort* Wb = sel ? Wkb : Wqb;
    const float* bias = sel ? bk : bq;
    ushort* dst = sel ? Kt : Qt;

    __shared__ float ldsT[64][65];  // [c][n], pad 1 -> 2-way max (free)
    const int t = threadIdx.x;
    const int w = __builtin_amdgcn_readfirstlane(t >> 6);  // wave 0..3
    const int l15 = t & 15;
    const int l4 = (t & 63) >> 4;

    f32x4 qacc[4];
#pragma unroll
    for (int j = 0; j < 4; ++j) qacc[j] = (f32x4){0.f, 0.f, 0.f, 0.f};

    for (int c0 = 0; c0 < CC; c0 += 64) {
        __syncthreads();
#pragma unroll
        for (int p = 0; p < 4; ++p) {
            int i = t + p * 256;          // 0..1023 float4s
            int c = i >> 4, n4 = (i & 15) * 4;
            float4 v = *reinterpret_cast<const float4*>(
                &src[((size_t)b * CC + c0 + c) * NN + n0 + n4]);
            ldsT[c][n4 + 0] = v.x;
            ldsT[c][n4 + 1] = v.y;
            ldsT[c][n4 + 2] = v.z;
            ldsT[c][n4 + 3] = v.w;
            if (sel) {
                ushort4 u;
                u.x = f2bf(v.x); u.y = f2bf(v.y); u.z = f2bf(v.z); u.w = f2bf(v.w);
                *reinterpret_cast<ushort4*>(
                    &audio_b[((size_t)b * CC + c0 + c) * NN + n0 + n4]) = u;
            }
        }
        __syncthreads();
#pragma unroll
        for (int ksub = 0; ksub < 2; ++ksub) {
            short8 af;
#pragma unroll
            for (int j = 0; j < 8; ++j)
                af[j] = (short)f2bf(ldsT[32 * ksub + 8 * l4 + j][16 * w + l15]);
#pragma unroll
            for (int cqj = 0; cqj < 4; ++cqj) {
                short8 wb = *reinterpret_cast<const short8*>(
                    &Wb[(size_t)(16 * cqj + l15) * CC + c0 + 32 * ksub + 8 * l4]);
                qacc[cqj] = MFMA16(af, wb, qacc[cqj]);
            }
        }
    }
#pragma unroll
    for (int cqj = 0; cqj < 4; ++cqj) {
        float bs = bias[16 * cqj + l15];
#pragma unroll
        for (int reg = 0; reg < 4; ++reg) {
            int n = n0 + 16 * w + 4 * l4 + reg;
            dst[((size_t)b * NN + n) * CQ + 16 * cqj + l15] =
                f2bf(qacc[cqj][reg] + bs);
        }
    }
}

// ---------------------------------------------------------------------------
// Fused attention + output GEMM. One block per (b, 64-n-tile): grid 512,
// block 512 (8 waves), 2 blocks/CU (LDS ~67 KB). Register-budgeted for the
// 128-reg cap of (512,4): zacc/facc 64 accum; arch live kept <= ~60.
//   S: P[64n][512m] = exp(Qt Kt^T / 8) per strip (2 strips); wave = 64 m-cols
//   l: row-sums by RE-READING P from LDS (wave w owns rows 8w..8w+7, full
//      width -> complete sums, no cross-wave combine, no lacc registers)
//   Z: zacc[c][n] += audio[c][m]*P[n][m]; wave (wc,wn) = 128c x 32n
//   O: out = gamma*(Wv . Znorm + bv) + face; Znorm staged in smem as [n][c]
// ---------------------------------------------------------------------------
__global__ __launch_bounds__(512, 4) void k_attn(
    const ushort* __restrict__ Qt, const ushort* __restrict__ Kt,
    const ushort* __restrict__ Ab_, const ushort* __restrict__ Wvb,
    const float* __restrict__ bv, const float* __restrict__ gamma,
    const float* __restrict__ face, float* __restrict__ out) {
    __shared__ ushort smem[64 * PSTR];  // P strip [64n][512m] / Znorm [64n][512c]
    __shared__ float l_acc[64];

    // bijective XCD-chunked swizzle (512 % 8 == 0): XCD x gets b in [4x,4x+4)
    const int wg = blockIdx.x;
    const int swz = (wg & 7) * 64 + (wg >> 3);
    const int b = swz >> 4;
    const int n0 = (swz & 15) * 64;

    const int t = threadIdx.x;
    const int w = __builtin_amdgcn_readfirstlane(t >> 6);  // wave 0..7
    const int l63 = t & 63;
    const int l15 = t & 15;
    const int l4 = (t & 63) >> 4;
    const int wc = w >> 1;  // c/o group (128 rows)
    const int wn = w & 1;   // n group (32 cols)

    const ushort* Qb = Qt + ((size_t)b * NN + n0) * CQ;
    const ushort* Kb = Kt + (size_t)b * NN * CQ;
    const ushort* Ab = Ab_ + (size_t)b * CC * NN;

    f32x4 zacc[8][2];  // [ci][nj]: c = 128wc+16ci, n = 32wn+16nj  (64 accum)
#pragma unroll
    for (int ci = 0; ci < 8; ++ci)
#pragma unroll
        for (int nj = 0; nj < 2; ++nj) zacc[ci][nj] = (f32x4){0.f, 0.f, 0.f, 0.f};

    // Q A-fragments, invariant across strips: 32 regs, all waves same tile (L1)
    short8 qa[4][2];
#pragma unroll
    for (int ni = 0; ni < 4; ++ni)
#pragma unroll
        for (int ks = 0; ks < 2; ++ks)
            qa[ni][ks] = *reinterpret_cast<const short8*>(
                &Qb[(size_t)(16 * ni + l15) * CQ + 32 * ks + 8 * l4]);

#pragma unroll 1
    for (int st = 0; st < 2; ++st) {
        const int m0 = st * 512;
        __syncthreads();  // prev strip's Z phase done reading smem
        // ---- S phase: wave w owns m-cols [64w, +64) of this strip
#pragma unroll 1
        for (int mj = 0; mj < 4; ++mj) {
            const ushort* kp =
                &Kb[(size_t)(m0 + 64 * w + 16 * mj + l15) * CQ + 8 * l4];
            short8 kb0 = *reinterpret_cast<const short8*>(kp);
            short8 kb1 = *reinterpret_cast<const short8*>(kp + 32);
#pragma unroll
            for (int ni = 0; ni < 4; ++ni) {
                f32x4 sacc = (f32x4){0.f, 0.f, 0.f, 0.f};
                sacc = MFMA16(qa[ni][0], kb0, sacc);
                sacc = MFMA16(qa[ni][1], kb1, sacc);
#pragma unroll
                for (int r = 0; r < 4; ++r) {
                    float p = exp2f(sacc[r] * 0.18033688011112f);  // exp(S/8)
                    smem[(16 * ni + 4 * l4 + r) * PSTR + 64 * w + 16 * mj + l15] =
                        f2bf(p);
                }
            }
        }
        __syncthreads();  // P strip visible
        // ---- l phase: wave w owns rows [8w, 8w+8); one b128 spans the row
#pragma unroll
        for (int r = 0; r < 8; ++r) {
            const int row = 8 * w + r;
            short8 pv = *reinterpret_cast<const short8*>(
                &smem[row * PSTR + 8 * l63]);
            float s = 0.f;
#pragma unroll
            for (int j = 0; j < 8; ++j) s += bf2f((ushort)pv[j]);
            s += __shfl_xor(s, 1, 64);
            s += __shfl_xor(s, 2, 64);
            s += __shfl_xor(s, 4, 64);
            s += __shfl_xor(s, 8, 64);
            s += __shfl_xor(s, 16, 64);
            s += __shfl_xor(s, 32, 64);
            if (l63 == 0) l_acc[row] = st ? (l_acc[row] + s) : s;
        }
        // ---- Z phase: wave (wc, wn): c-rows [128wc,+128), n-cols [32wn,+32)
#pragma unroll 2
        for (int ks = 0; ks < 16; ++ks) {
            short8 pb[2];
#pragma unroll
            for (int nj = 0; nj < 2; ++nj)
                pb[nj] = *reinterpret_cast<const short8*>(
                    &smem[(32 * wn + 16 * nj + l15) * PSTR + 32 * ks + 8 * l4]);
#pragma unroll
            for (int cih = 0; cih < 2; ++cih) {
                short8 af[4];
#pragma unroll
                for (int ci = 0; ci < 4; ++ci)
                    af[ci] = *reinterpret_cast<const short8*>(
                        &Ab[(size_t)(128 * wc + 64 * cih + 16 * ci + l15) * NN +
                            m0 + 32 * ks + 8 * l4]);
#pragma unroll
                for (int ci = 0; ci < 4; ++ci)
#pragma unroll
                    for (int nj = 0; nj < 2; ++nj)
                        zacc[4 * cih + ci][nj] =
                            MFMA16(af[ci], pb[nj], zacc[4 * cih + ci][nj]);
            }
        }
    }

    __syncthreads();  // all Z reads of smem done; l_acc complete

    // ---- normalize + stage Znorm to smem as [n][c]
    float li[2];
#pragma unroll
    for (int nj = 0; nj < 2; ++nj) li[nj] = 1.f / l_acc[32 * wn + 16 * nj + l15];
#pragma unroll
    for (int ci = 0; ci < 8; ++ci)
#pragma unroll
        for (int nj = 0; nj < 2; ++nj) {
            ushort4 o4;
            o4.x = f2bf(zacc[ci][nj][0] * li[nj]);
            o4.y = f2bf(zacc[ci][nj][1] * li[nj]);
            o4.z = f2bf(zacc[ci][nj][2] * li[nj]);
            o4.w = f2bf(zacc[ci][nj][3] * li[nj]);
            *reinterpret_cast<ushort4*>(
                &smem[(32 * wn + 16 * nj + l15) * PSTR + 128 * wc + 16 * ci + 4 * l4]) = o4;
        }
    __syncthreads();

    // ---- O phase: o-rows [128wc,+128), n-cols [32wn,+32); D rows = n (swap)
    f32x4 facc[8][2];
#pragma unroll
    for (int oi = 0; oi < 8; ++oi)
#pragma unroll
        for (int nj = 0; nj < 2; ++nj) facc[oi][nj] = (f32x4){0.f, 0.f, 0.f, 0.f};
#pragma unroll 2
    for (int ks = 0; ks < 16; ++ks) {
        short8 zb[2];
#pragma unroll
        for (int nj = 0; nj < 2; ++nj)
            zb[nj] = *reinterpret_cast<const short8*>(
                &smem[(32 * wn + 16 * nj + l15) * PSTR + 32 * ks + 8 * l4]);
#pragma unroll
        for (int oih = 0; oih < 2; ++oih) {
            short8 wa[4];
#pragma unroll
            for (int oi = 0; oi < 4; ++oi)
                wa[oi] = *reinterpret_cast<const short8*>(
                    &Wvb[(size_t)(128 * wc + 64 * oih + 16 * oi + l15) * CC +
                         32 * ks + 8 * l4]);
#pragma unroll
            for (int oi = 0; oi < 4; ++oi)
#pragma unroll
                for (int nj = 0; nj < 2; ++nj)
                    facc[4 * oih + oi][nj] =
                        MFMA16(zb[nj], wa[oi], facc[4 * oih + oi][nj]);
        }
    }

    // ---- epilogue: float4 along n (D rows = n via 4l4+reg)
    const float g = gamma[0];
#pragma unroll
    for (int oi = 0; oi < 8; ++oi) {
        int o = 128 * wc + 16 * oi + l15;
        float bvo = bv[o];
#pragma unroll
        for (int nj = 0; nj < 2; ++nj) {
            int n = n0 + 32 * wn + 16 * nj + 4 * l4;
            size_t idx = ((size_t)b * CC + o) * NN + n;
            float4 fc = *reinterpret_cast<const float4*>(&face[idx]);
            float4 ov;
            ov.x = g * (facc[oi][nj][0] + bvo) + fc.x;
            ov.y = g * (facc[oi][nj][1] + bvo) + fc.y;
            ov.z = g * (facc[oi][nj][2] + bvo) + fc.z;
            ov.w = g * (facc[oi][nj][3] + bvo) + fc.w;
            *reinterpret_cast<float4*>(&out[idx]) = ov;
        }
    }
}

// ---------------------------------------------------------------------------
extern "C" void kernel_launch(void* const* d_in, const int* in_sizes, int n_in,
                              void* d_out, int out_size, void* d_ws, size_t ws_size,
                              hipStream_t stream) {
    const float* face  = (const float*)d_in[0];
    const float* audio = (const float*)d_in[1];
    const float* Wq    = (const float*)d_in[2];
    const float* bq    = (const float*)d_in[3];
    const float* Wk    = (const float*)d_in[4];
    const float* bk    = (const float*)d_in[5];
    const float* Wv    = (const float*)d_in[6];
    const float* bv    = (const float*)d_in[7];
    const float* gamma = (const float*)d_in[8];
    float* out = (float*)d_out;
    char* ws = (char*)d_ws;

    // workspace layout (bytes)
    ushort* Qt      = (ushort*)(ws + 0);                       // 4 MB
    ushort* Kt      = (ushort*)(ws + (4u << 20));              // 4 MB
    ushort* audio_b = (ushort*)(ws + (8u << 20));              // 32 MB
    ushort* Wqb     = (ushort*)(ws + (40u << 20));             // 64 KB
    ushort* Wkb     = (ushort*)(ws + (40u << 20) + (64u << 10));
    ushort* Wvb     = (ushort*)(ws + (40u << 20) + (128u << 10));  // 512 KB

    hipLaunchKernelGGL(k_cvt3, dim3(320), dim3(256), 0, stream,
                       Wq, Wk, Wv, Wqb, Wkb, Wvb);
    hipLaunchKernelGGL(k_proj, dim3(16, 2, BB), dim3(256), 0, stream,
                       face, audio, Wqb, bq, Wkb, bk, Qt, Kt, audio_b);
    hipLaunchKernelGGL(k_attn, dim3(512), dim3(512), 0, stream,
                       Qt, Kt, audio_b, Wvb, bv, gamma, face, out);
}

// Round 6
// 206.875 us; speedup vs baseline: 1.5508x; 1.3745x over previous
//
#include <hip/hip_runtime.h>
#include <math.h>

// Problem constants (fixed by reference)
#define BB 32     // batch
#define CC 512    // channels
#define CQ 64     // qk channels
#define NN 1024   // Nq = Nk = 32*32

typedef __attribute__((ext_vector_type(8))) short short8;   // 8 bf16 = 4 VGPR
typedef __attribute__((ext_vector_type(4))) float f32x4;    // MFMA C/D frag

#define MFMA16(a, b, c) __builtin_amdgcn_mfma_f32_16x16x32_bf16(a, b, c, 0, 0, 0)

// P/Znorm LDS row stride in ushorts: 512 + 8 pad -> 1040 B (16B aligned).
#define PSTR 520
// audio_b row stride in elems: 1024 + 32 -> 2112 B, breaks 2KB L2 set aliasing
#define ASTR 1056

__device__ __forceinline__ ushort f2bf(float f) {
    uint u = __builtin_bit_cast(uint, f);
    return (ushort)((u + 0x7FFFu + ((u >> 16) & 1u)) >> 16);  // RNE
}
__device__ __forceinline__ float bf2f(ushort u) {
    return __builtin_bit_cast(float, ((uint)u) << 16);
}
__device__ __forceinline__ short8 ld8(const ushort* p) {
    return *reinterpret_cast<const short8*>(p);
}

// ---------------------------------------------------------------------------
// All three weight tensors f32 -> bf16 in one launch. grid 320 x 256 exact.
// ---------------------------------------------------------------------------
__global__ __launch_bounds__(256) void k_cvt3(const float* __restrict__ Wq,
                                              const float* __restrict__ Wk,
                                              const float* __restrict__ Wv,
                                              ushort* __restrict__ Wqb,
                                              ushort* __restrict__ Wkb,
                                              ushort* __restrict__ Wvb) {
    int i = blockIdx.x * 256 + threadIdx.x;  // f4 index over 81920
    const float* src;
    ushort* dst;
    int off;
    if (i < 8192) { src = Wq; dst = Wqb; off = i; }
    else if (i < 16384) { src = Wk; dst = Wkb; off = i - 8192; }
    else { src = Wv; dst = Wvb; off = i - 16384; }
    float4 v = reinterpret_cast<const float4*>(src)[off];
    ushort4 o;
    o.x = f2bf(v.x); o.y = f2bf(v.y); o.z = f2bf(v.z); o.w = f2bf(v.w);
    reinterpret_cast<ushort4*>(dst)[off] = o;
}

// ---------------------------------------------------------------------------
// Qt[b][n][cq] = sum_c src[b][c][n]*W[cq][c] + bias[cq]   (bf16 out)
// sel=1 additionally emits audio_b (bf16 copy, ASTR-padded rows).
// grid (16 ntiles, 2 sel, B), block 256 (4 waves).
// ---------------------------------------------------------------------------
__global__ __launch_bounds__(256) void k_proj(const float* __restrict__ face,
                                              const float* __restrict__ audio,
                                              const ushort* __restrict__ Wqb,
                                              const float* __restrict__ bq,
                                              const ushort* __restrict__ Wkb,
                                              const float* __restrict__ bk,
                                              ushort* __restrict__ Qt,
                                              ushort* __restrict__ Kt,
                                              ushort* __restrict__ audio_b) {
    const int sel = blockIdx.y;
    const int b = blockIdx.z;
    const int n0 = blockIdx.x * 64;
    const float* src = sel ? audio : face;
    const ushort* Wb = sel ? Wkb : Wqb;
    const float* bias = sel ? bk : bq;
    ushort* dst = sel ? Kt : Qt;

    __shared__ float ldsT[64][65];  // [c][n], pad 1 -> 2-way max (free)
    const int t = threadIdx.x;
    const int w = __builtin_amdgcn_readfirstlane(t >> 6);  // wave 0..3
    const int l15 = t & 15;
    const int l4 = (t & 63) >> 4;

    f32x4 qacc[4];
#pragma unroll
    for (int j = 0; j < 4; ++j) qacc[j] = (f32x4){0.f, 0.f, 0.f, 0.f};

    for (int c0 = 0; c0 < CC; c0 += 64) {
        __syncthreads();
#pragma unroll
        for (int p = 0; p < 4; ++p) {
            int i = t + p * 256;          // 0..1023 float4s
            int c = i >> 4, n4 = (i & 15) * 4;
            float4 v = *reinterpret_cast<const float4*>(
                &src[((size_t)b * CC + c0 + c) * NN + n0 + n4]);
            ldsT[c][n4 + 0] = v.x;
            ldsT[c][n4 + 1] = v.y;
            ldsT[c][n4 + 2] = v.z;
            ldsT[c][n4 + 3] = v.w;
            if (sel) {
                ushort4 u;
                u.x = f2bf(v.x); u.y = f2bf(v.y); u.z = f2bf(v.z); u.w = f2bf(v.w);
                *reinterpret_cast<ushort4*>(
                    &audio_b[((size_t)b * CC + c0 + c) * ASTR + n0 + n4]) = u;
            }
        }
        __syncthreads();
#pragma unroll
        for (int ksub = 0; ksub < 2; ++ksub) {
            short8 af;
#pragma unroll
            for (int j = 0; j < 8; ++j)
                af[j] = (short)f2bf(ldsT[32 * ksub + 8 * l4 + j][16 * w + l15]);
#pragma unroll
            for (int cqj = 0; cqj < 4; ++cqj) {
                short8 wb = ld8(&Wb[(size_t)(16 * cqj + l15) * CC + c0 + 32 * ksub + 8 * l4]);
                qacc[cqj] = MFMA16(af, wb, qacc[cqj]);
            }
        }
    }
#pragma unroll
    for (int cqj = 0; cqj < 4; ++cqj) {
        float bs = bias[16 * cqj + l15];
#pragma unroll
        for (int reg = 0; reg < 4; ++reg) {
            int n = n0 + 16 * w + 4 * l4 + reg;
            dst[((size_t)b * NN + n) * CQ + 16 * cqj + l15] =
                f2bf(qacc[cqj][reg] + bs);
        }
    }
}

// ---------------------------------------------------------------------------
// Fused attention + output GEMM. One block per (b, 64-n-tile): grid 512,
// block 512 (8 waves), 2 blocks/CU (LDS ~67 KB). Register budget: 64 acc
// (AGPR) + <=~60 arch VGPR at any point -> fits the 128 cap of (512,4).
//   S: P[64n][512m] = exp(Qt Kt^T / 8) per strip; wave = 64 m-cols,
//      kb prefetched 1 mj ahead; qa reloaded per strip (dead during Z).
//   l: row-sums re-read from LDS (wave w owns rows 8w..8w+7)
//   Z: wave w owns c-rows [64w,+64) x ALL 64 n (no duplication);
//      af double-buffered 1 ks ahead; 4 af + 4 pb loads per 16 MFMA.
//   O: out = gamma*(Wv . Znorm + bv) + face; wa double-buffered; facc
//      reuses the zacc accumulator registers.
// ---------------------------------------------------------------------------
__global__ __launch_bounds__(512, 4) void k_attn(
    const ushort* __restrict__ Qt, const ushort* __restrict__ Kt,
    const ushort* __restrict__ Ab_, const ushort* __restrict__ Wvb,
    const float* __restrict__ bv, const float* __restrict__ gamma,
    const float* __restrict__ face, float* __restrict__ out) {
    __shared__ ushort smem[64 * PSTR];  // P strip [64n][512m] / Znorm [64n][512c]
    __shared__ float l_acc[64];

    // bijective XCD-chunked swizzle: XCD x gets b in [4x, 4x+4)
    const int wg = blockIdx.x;
    const int swz = (wg & 7) * 64 + (wg >> 3);
    const int b = swz >> 4;
    const int n0 = (swz & 15) * 64;

    const int t = threadIdx.x;
    const int w = __builtin_amdgcn_readfirstlane(t >> 6);  // wave 0..7
    const int l63 = t & 63;
    const int l15 = t & 15;
    const int l4 = (t & 63) >> 4;

    const ushort* Qb = Qt + ((size_t)b * NN + n0) * CQ;
    const ushort* Kb = Kt + (size_t)b * NN * CQ;
    const ushort* Ab = Ab_ + (size_t)b * CC * ASTR;

    f32x4 acc[4][4];  // Z: c = 64w+16ci+4l4+reg, n = 16nj+l15 (64 AGPR)
#pragma unroll
    for (int ci = 0; ci < 4; ++ci)
#pragma unroll
        for (int nj = 0; nj < 4; ++nj) acc[ci][nj] = (f32x4){0.f, 0.f, 0.f, 0.f};

#pragma unroll 1
    for (int st = 0; st < 2; ++st) {
        const int m0 = st * 512;
        __syncthreads();  // prev strip's Z done reading smem
        // ---- S phase: wave w owns m-cols [64w, +64) of this strip
        short8 qa[4][2];
#pragma unroll
        for (int ni = 0; ni < 4; ++ni)
#pragma unroll
            for (int kk = 0; kk < 2; ++kk)
                qa[ni][kk] = ld8(&Qb[(size_t)(16 * ni + l15) * CQ + 32 * kk + 8 * l4]);
        const ushort* kp0 = &Kb[(size_t)(m0 + 64 * w + l15) * CQ + 8 * l4];
        short8 kc0 = ld8(kp0), kc1 = ld8(kp0 + 32);
#pragma unroll
        for (int mj = 0; mj < 4; ++mj) {
            short8 kn0, kn1;
            if (mj < 3) {
                const ushort* kp = kp0 + (size_t)(16 * (mj + 1)) * CQ;
                kn0 = ld8(kp);
                kn1 = ld8(kp + 32);
            }
#pragma unroll
            for (int ni = 0; ni < 4; ++ni) {
                f32x4 sacc = (f32x4){0.f, 0.f, 0.f, 0.f};
                sacc = MFMA16(qa[ni][0], kc0, sacc);
                sacc = MFMA16(qa[ni][1], kc1, sacc);
#pragma unroll
                for (int r = 0; r < 4; ++r) {
                    float p = exp2f(sacc[r] * 0.18033688011112f);  // exp(S/8)
                    smem[(16 * ni + 4 * l4 + r) * PSTR + 64 * w + 16 * mj + l15] =
                        f2bf(p);
                }
            }
            if (mj < 3) { kc0 = kn0; kc1 = kn1; }
        }
        __syncthreads();  // P strip visible
        // ---- l phase: wave w owns rows [8w, 8w+8); one b128 spans the row
#pragma unroll
        for (int r = 0; r < 8; ++r) {
            const int row = 8 * w + r;
            short8 pv = ld8(&smem[row * PSTR + 8 * l63]);
            float s = 0.f;
#pragma unroll
            for (int j = 0; j < 8; ++j) s += bf2f((ushort)pv[j]);
            s += __shfl_xor(s, 1, 64);
            s += __shfl_xor(s, 2, 64);
            s += __shfl_xor(s, 4, 64);
            s += __shfl_xor(s, 8, 64);
            s += __shfl_xor(s, 16, 64);
            s += __shfl_xor(s, 32, 64);
            if (l63 == 0) l_acc[row] = st ? (l_acc[row] + s) : s;
        }
        // ---- Z phase: wave w owns c-rows [64w,+64) x all 64 n; af dbuf
        short8 afp[2][4];
#pragma unroll
        for (int ci = 0; ci < 4; ++ci)
            afp[0][ci] = ld8(&Ab[(size_t)(64 * w + 16 * ci + l15) * ASTR + m0 + 8 * l4]);
        __builtin_amdgcn_s_setprio(1);
#pragma unroll
        for (int ks = 0; ks < 16; ++ks) {
            const int cur = ks & 1;
            if (ks < 15) {
#pragma unroll
                for (int ci = 0; ci < 4; ++ci)
                    afp[cur ^ 1][ci] = ld8(
                        &Ab[(size_t)(64 * w + 16 * ci + l15) * ASTR + m0 +
                            32 * (ks + 1) + 8 * l4]);
            }
            short8 pb[4];
#pragma unroll
            for (int nj = 0; nj < 4; ++nj)
                pb[nj] = ld8(&smem[(16 * nj + l15) * PSTR + 32 * ks + 8 * l4]);
#pragma unroll
            for (int ci = 0; ci < 4; ++ci)
#pragma unroll
                for (int nj = 0; nj < 4; ++nj)
                    acc[ci][nj] = MFMA16(afp[cur][ci], pb[nj], acc[ci][nj]);
        }
        __builtin_amdgcn_s_setprio(0);
    }

    __syncthreads();  // Z reads of smem done; l_acc complete

    // ---- normalize + stage Znorm to smem as [n][c]
    float li[4];
#pragma unroll
    for (int nj = 0; nj < 4; ++nj) li[nj] = 1.f / l_acc[16 * nj + l15];
#pragma unroll
    for (int ci = 0; ci < 4; ++ci)
#pragma unroll
        for (int nj = 0; nj < 4; ++nj) {
            ushort4 o4;
            o4.x = f2bf(acc[ci][nj][0] * li[nj]);
            o4.y = f2bf(acc[ci][nj][1] * li[nj]);
            o4.z = f2bf(acc[ci][nj][2] * li[nj]);
            o4.w = f2bf(acc[ci][nj][3] * li[nj]);
            *reinterpret_cast<ushort4*>(
                &smem[(16 * nj + l15) * PSTR + 64 * w + 16 * ci + 4 * l4]) = o4;
        }
    __syncthreads();

    // ---- O phase: wave w owns o-rows [64w,+64) x all 64 n; wa dbuf
#pragma unroll
    for (int oi = 0; oi < 4; ++oi)
#pragma unroll
        for (int nj = 0; nj < 4; ++nj) acc[oi][nj] = (f32x4){0.f, 0.f, 0.f, 0.f};
    short8 wap[2][4];
#pragma unroll
    for (int oi = 0; oi < 4; ++oi)
        wap[0][oi] = ld8(&Wvb[(size_t)(64 * w + 16 * oi + l15) * CC + 8 * l4]);
    __builtin_amdgcn_s_setprio(1);
#pragma unroll
    for (int ks = 0; ks < 16; ++ks) {
        const int cur = ks & 1;
        if (ks < 15) {
#pragma unroll
            for (int oi = 0; oi < 4; ++oi)
                wap[cur ^ 1][oi] = ld8(
                    &Wvb[(size_t)(64 * w + 16 * oi + l15) * CC + 32 * (ks + 1) + 8 * l4]);
        }
        short8 zb[4];
#pragma unroll
        for (int nj = 0; nj < 4; ++nj)
            zb[nj] = ld8(&smem[(16 * nj + l15) * PSTR + 32 * ks + 8 * l4]);
        // D rows = n (A = zb), cols = o (B = wa)
#pragma unroll
        for (int oi = 0; oi < 4; ++oi)
#pragma unroll
            for (int nj = 0; nj < 4; ++nj)
                acc[oi][nj] = MFMA16(zb[nj], wap[cur][oi], acc[oi][nj]);
    }
    __builtin_amdgcn_s_setprio(0);

    // ---- epilogue: float4 along n
    const float g = gamma[0];
#pragma unroll
    for (int oi = 0; oi < 4; ++oi) {
        int o = 64 * w + 16 * oi + l15;
        float bvo = bv[o];
#pragma unroll
        for (int nj = 0; nj < 4; ++nj) {
            int n = n0 + 16 * nj + 4 * l4;
            size_t idx = ((size_t)b * CC + o) * NN + n;
            float4 fc = *reinterpret_cast<const float4*>(&face[idx]);
            float4 ov;
            ov.x = g * (acc[oi][nj][0] + bvo) + fc.x;
            ov.y = g * (acc[oi][nj][1] + bvo) + fc.y;
            ov.z = g * (acc[oi][nj][2] + bvo) + fc.z;
            ov.w = g * (acc[oi][nj][3] + bvo) + fc.w;
            *reinterpret_cast<float4*>(&out[idx]) = ov;
        }
    }
}

// ---------------------------------------------------------------------------
extern "C" void kernel_launch(void* const* d_in, const int* in_sizes, int n_in,
                              void* d_out, int out_size, void* d_ws, size_t ws_size,
                              hipStream_t stream) {
    const float* face  = (const float*)d_in[0];
    const float* audio = (const float*)d_in[1];
    const float* Wq    = (const float*)d_in[2];
    const float* bq    = (const float*)d_in[3];
    const float* Wk    = (const float*)d_in[4];
    const float* bk    = (const float*)d_in[5];
    const float* Wv    = (const float*)d_in[6];
    const float* bv    = (const float*)d_in[7];
    const float* gamma = (const float*)d_in[8];
    float* out = (float*)d_out;
    char* ws = (char*)d_ws;

    // workspace layout (bytes)
    ushort* Qt      = (ushort*)(ws + 0);                       // 4 MB
    ushort* Kt      = (ushort*)(ws + (4u << 20));              // 4 MB
    ushort* audio_b = (ushort*)(ws + (8u << 20));              // ~33 MB (padded)
    ushort* Wqb     = (ushort*)(ws + (44u << 20));             // 64 KB
    ushort* Wkb     = (ushort*)(ws + (44u << 20) + (64u << 10));
    ushort* Wvb     = (ushort*)(ws + (44u << 20) + (128u << 10));  // 512 KB

    hipLaunchKernelGGL(k_cvt3, dim3(320), dim3(256), 0, stream,
                       Wq, Wk, Wv, Wqb, Wkb, Wvb);
    hipLaunchKernelGGL(k_proj, dim3(16, 2, BB), dim3(256), 0, stream,
                       face, audio, Wqb, bq, Wkb, bk, Qt, Kt, audio_b);
    hipLaunchKernelGGL(k_attn, dim3(512), dim3(512), 0, stream,
                       Qt, Kt, audio_b, Wvb, bv, gamma, face, out);
}

// Round 7
// 177.007 us; speedup vs baseline: 1.8125x; 1.1687x over previous
//
#include <hip/hip_runtime.h>
#include <math.h>

// Problem constants (fixed by reference)
#define BB 32     // batch
#define CC 512    // channels
#define CQ 64     // qk channels
#define NN 1024   // Nq = Nk = 32*32

typedef __attribute__((ext_vector_type(8))) short short8;   // 8 bf16 = 4 VGPR
typedef __attribute__((ext_vector_type(4))) float f32x4;    // MFMA C/D frag

#define MFMA16(a, b, c) __builtin_amdgcn_mfma_f32_16x16x32_bf16(a, b, c, 0, 0, 0)

// P strip LDS row stride (ushorts): 256 m + 8 pad = 264 (528 B)
#define PSTR 264
#define PBUF (64 * PSTR)   // one strip buffer, ushorts
// Znorm row stride (ushorts): 512 c + 8 pad
#define ZSTR 520
// audio_b row stride in elems: 1024 + 32 -> 2112 B, breaks 2KB L2 set aliasing
#define ASTR 1056

__device__ __forceinline__ ushort f2bf(float f) {
    uint u = __builtin_bit_cast(uint, f);
    return (ushort)((u + 0x7FFFu + ((u >> 16) & 1u)) >> 16);  // RNE
}
__device__ __forceinline__ short8 ld8(const ushort* p) {
    return *reinterpret_cast<const short8*>(p);
}

// ---------------------------------------------------------------------------
// All three weight tensors f32 -> bf16 in one launch. grid 320 x 256 exact.
// ---------------------------------------------------------------------------
__global__ __launch_bounds__(256) void k_cvt3(const float* __restrict__ Wq,
                                              const float* __restrict__ Wk,
                                              const float* __restrict__ Wv,
                                              ushort* __restrict__ Wqb,
                                              ushort* __restrict__ Wkb,
                                              ushort* __restrict__ Wvb) {
    int i = blockIdx.x * 256 + threadIdx.x;  // f4 index over 81920
    const float* src;
    ushort* dst;
    int off;
    if (i < 8192) { src = Wq; dst = Wqb; off = i; }
    else if (i < 16384) { src = Wk; dst = Wkb; off = i - 8192; }
    else { src = Wv; dst = Wvb; off = i - 16384; }
    float4 v = reinterpret_cast<const float4*>(src)[off];
    ushort4 o;
    o.x = f2bf(v.x); o.y = f2bf(v.y); o.z = f2bf(v.z); o.w = f2bf(v.w);
    reinterpret_cast<ushort4*>(dst)[off] = o;
}

// ---------------------------------------------------------------------------
// Qt[b][n][cq] = sum_c src[b][c][n]*W[cq][c] + bias[cq]   (bf16 out)
// sel=1 additionally emits audio_b (bf16 copy, ASTR-padded rows).
// grid (16 ntiles, 2 sel, B), block 256 (4 waves).
// ---------------------------------------------------------------------------
__global__ __launch_bounds__(256) void k_proj(const float* __restrict__ face,
                                              const float* __restrict__ audio,
                                              const ushort* __restrict__ Wqb,
                                              const float* __restrict__ bq,
                                              const ushort* __restrict__ Wkb,
                                              const float* __restrict__ bk,
                                              ushort* __restrict__ Qt,
                                              ushort* __restrict__ Kt,
                                              ushort* __restrict__ audio_b) {
    const int sel = blockIdx.y;
    const int b = blockIdx.z;
    const int n0 = blockIdx.x * 64;
    const float* src = sel ? audio : face;
    const ushort* Wb = sel ? Wkb : Wqb;
    const float* bias = sel ? bk : bq;
    ushort* dst = sel ? Kt : Qt;

    __shared__ float ldsT[64][65];  // [c][n], pad 1 -> 2-way max (free)
    const int t = threadIdx.x;
    const int w = __builtin_amdgcn_readfirstlane(t >> 6);  // wave 0..3
    const int l15 = t & 15;
    const int l4 = (t & 63) >> 4;

    f32x4 qacc[4];
#pragma unroll
    for (int j = 0; j < 4; ++j) qacc[j] = (f32x4){0.f, 0.f, 0.f, 0.f};

    for (int c0 = 0; c0 < CC; c0 += 64) {
        __syncthreads();
#pragma unroll
        for (int p = 0; p < 4; ++p) {
            int i = t + p * 256;          // 0..1023 float4s
            int c = i >> 4, n4 = (i & 15) * 4;
            float4 v = *reinterpret_cast<const float4*>(
                &src[((size_t)b * CC + c0 + c) * NN + n0 + n4]);
            ldsT[c][n4 + 0] = v.x;
            ldsT[c][n4 + 1] = v.y;
            ldsT[c][n4 + 2] = v.z;
            ldsT[c][n4 + 3] = v.w;
            if (sel) {
                ushort4 u;
                u.x = f2bf(v.x); u.y = f2bf(v.y); u.z = f2bf(v.z); u.w = f2bf(v.w);
                *reinterpret_cast<ushort4*>(
                    &audio_b[((size_t)b * CC + c0 + c) * ASTR + n0 + n4]) = u;
            }
        }
        __syncthreads();
#pragma unroll
        for (int ksub = 0; ksub < 2; ++ksub) {
            short8 af;
#pragma unroll
            for (int j = 0; j < 8; ++j)
                af[j] = (short)f2bf(ldsT[32 * ksub + 8 * l4 + j][16 * w + l15]);
#pragma unroll
            for (int cqj = 0; cqj < 4; ++cqj) {
                short8 wb = ld8(&Wb[(size_t)(16 * cqj + l15) * CC + c0 + 32 * ksub + 8 * l4]);
                qacc[cqj] = MFMA16(af, wb, qacc[cqj]);
            }
        }
    }
#pragma unroll
    for (int cqj = 0; cqj < 4; ++cqj) {
        float bs = bias[16 * cqj + l15];
#pragma unroll
        for (int reg = 0; reg < 4; ++reg) {
            int n = n0 + 16 * w + 4 * l4 + reg;
            dst[((size_t)b * NN + n) * CQ + 16 * cqj + l15] =
                f2bf(qacc[cqj][reg] + bs);
        }
    }
}

// ---------------------------------------------------------------------------
// Fused attention + output GEMM, software-pipelined S||Z.
// One block per (b, 64-n-tile): grid 512, block 256 (4 waves), 2 blocks/CU
// (LDS ~69 KB), VGPR budget 256 (2 waves/SIMD -- HK operating point).
//   P double-buffered in LDS: 4 strips x 256 m. Iteration t: Z(t) consumes
//   buf[t&1] while S(t+1) (interleaved per-ks) fills buf[(t+1)&1].
//   One barrier per strip. Softmax row-sums held in registers (lacc).
//   Epilogue: Znorm staged over the P buffers, O = Wv.Znorm GEMM fused with
//   gamma*(.+bv)+face.
// ---------------------------------------------------------------------------
__global__ __launch_bounds__(256, 2) void k_attn(
    const ushort* __restrict__ Qt, const ushort* __restrict__ Kt,
    const ushort* __restrict__ Ab_, const ushort* __restrict__ Wvb,
    const float* __restrict__ bv, const float* __restrict__ gamma,
    const float* __restrict__ face, float* __restrict__ out) {
    __shared__ ushort smem[2 * PBUF];  // P dbuf; aliased as Znorm [64][ZSTR]
    __shared__ float l_part[4][64];

    // bijective XCD-chunked swizzle: XCD x gets b in [4x, 4x+4)
    const int wg = blockIdx.x;
    const int swz = (wg & 7) * 64 + (wg >> 3);
    const int b = swz >> 4;
    const int n0 = (swz & 15) * 64;

    const int t = threadIdx.x;
    const int w = __builtin_amdgcn_readfirstlane(t >> 6);  // wave 0..3
    const int l15 = t & 15;
    const int l4 = (t & 63) >> 4;

    const ushort* Qb = Qt + ((size_t)b * NN + n0) * CQ;
    const ushort* Kb = Kt + (size_t)b * NN * CQ;
    const ushort* Ab = Ab_ + (size_t)b * CC * ASTR;

    f32x4 acc[8][4];   // Z: c = 128w+16ci+4l4+reg, n = 16nj+l15  (128 VGPR)
#pragma unroll
    for (int ci = 0; ci < 8; ++ci)
#pragma unroll
        for (int nj = 0; nj < 4; ++nj) acc[ci][nj] = (f32x4){0.f, 0.f, 0.f, 0.f};
    float lacc[4][4];  // P row-sums, rows 16ni+4l4+r, own 64 m-cols x 4 strips
#pragma unroll
    for (int ni = 0; ni < 4; ++ni)
#pragma unroll
        for (int r = 0; r < 4; ++r) lacc[ni][r] = 0.f;

    // S chunk: compute P for m-cols [m0 + 64w + 16mj, +16) of strip at m0,
    // write bf16 into wbuf, accumulate lacc. qa reloaded per chunk (L1-hot).
#define S_CHUNK(m0, wbuf, mj)                                                  \
    {                                                                          \
        const ushort* kp =                                                     \
            &Kb[(size_t)((m0) + 64 * w + 16 * (mj) + l15) * CQ + 8 * l4];      \
        short8 kb0 = ld8(kp);                                                  \
        short8 kb1 = ld8(kp + 32);                                             \
        _Pragma("unroll") for (int ni = 0; ni < 4; ++ni) {                     \
            const ushort* qp = &Qb[(size_t)(16 * ni + l15) * CQ + 8 * l4];     \
            short8 qa0 = ld8(qp);                                              \
            short8 qa1 = ld8(qp + 32);                                         \
            f32x4 sacc = (f32x4){0.f, 0.f, 0.f, 0.f};                          \
            sacc = MFMA16(qa0, kb0, sacc);                                     \
            sacc = MFMA16(qa1, kb1, sacc);                                     \
            _Pragma("unroll") for (int r = 0; r < 4; ++r) {                    \
                float p = exp2f(sacc[r] * 0.18033688011112f);                  \
                lacc[ni][r] += p;                                              \
                (wbuf)[(16 * ni + 4 * l4 + r) * PSTR + 64 * w + 16 * (mj) +    \
                       l15] = f2bf(p);                                         \
            }                                                                  \
        }                                                                      \
    }

    // ---- prologue: S strip 0 into buf0
#pragma unroll
    for (int mj = 0; mj < 4; ++mj) S_CHUNK(0, smem, mj)
    __syncthreads();

    // ---- main loop: Z(t) from rbuf || S(t+1) into wbuf
#pragma unroll 1
    for (int tt = 0; tt < 4; ++tt) {
        ushort* rbuf = smem + (tt & 1) * PBUF;
        ushort* wbuf = smem + ((tt + 1) & 1) * PBUF;
        const int m0r = tt * 256;
        const bool do_s = (tt < 3);
#pragma unroll
        for (int ks = 0; ks < 8; ++ks) {
            // issue all Z loads first: af (global/L2) + pb (LDS)
            short8 afl[4], afh[4];
#pragma unroll
            for (int ci = 0; ci < 4; ++ci)
                afl[ci] = ld8(&Ab[(size_t)(128 * w + 16 * ci + l15) * ASTR +
                                  m0r + 32 * ks + 8 * l4]);
            short8 pb[4];
#pragma unroll
            for (int nj = 0; nj < 4; ++nj)
                pb[nj] = ld8(&rbuf[(16 * nj + l15) * PSTR + 32 * ks + 8 * l4]);
#pragma unroll
            for (int ci = 0; ci < 4; ++ci)
                afh[ci] = ld8(&Ab[(size_t)(128 * w + 64 + 16 * ci + l15) * ASTR +
                                  m0r + 32 * ks + 8 * l4]);
            // S chunk for next strip fills the load shadow (ks 0..3 only)
            if (ks < 4 && do_s) S_CHUNK(256 * (tt + 1), wbuf, ks)
            __builtin_amdgcn_s_setprio(1);
#pragma unroll
            for (int ci = 0; ci < 4; ++ci)
#pragma unroll
                for (int nj = 0; nj < 4; ++nj)
                    acc[ci][nj] = MFMA16(afl[ci], pb[nj], acc[ci][nj]);
#pragma unroll
            for (int ci = 0; ci < 4; ++ci)
#pragma unroll
                for (int nj = 0; nj < 4; ++nj)
                    acc[4 + ci][nj] = MFMA16(afh[ci], pb[nj], acc[4 + ci][nj]);
            __builtin_amdgcn_s_setprio(0);
        }
        __syncthreads();
    }

    // ---- softmax denominators: reduce lacc over l15 (m within wave), share
#pragma unroll
    for (int ni = 0; ni < 4; ++ni)
#pragma unroll
        for (int r = 0; r < 4; ++r) {
            float v = lacc[ni][r];
            v += __shfl_xor(v, 1, 64);
            v += __shfl_xor(v, 2, 64);
            v += __shfl_xor(v, 4, 64);
            v += __shfl_xor(v, 8, 64);
            if (l15 == 0) l_part[w][16 * ni + 4 * l4 + r] = v;
        }
    __syncthreads();

    // ---- normalize + stage Znorm over the (now dead) P buffers as [n][c]
    float li[4];
#pragma unroll
    for (int nj = 0; nj < 4; ++nj) {
        int n = 16 * nj + l15;
        li[nj] = 1.f / (l_part[0][n] + l_part[1][n] + l_part[2][n] + l_part[3][n]);
    }
#pragma unroll
    for (int ci = 0; ci < 8; ++ci)
#pragma unroll
        for (int nj = 0; nj < 4; ++nj) {
            ushort4 o4;
            o4.x = f2bf(acc[ci][nj][0] * li[nj]);
            o4.y = f2bf(acc[ci][nj][1] * li[nj]);
            o4.z = f2bf(acc[ci][nj][2] * li[nj]);
            o4.w = f2bf(acc[ci][nj][3] * li[nj]);
            *reinterpret_cast<ushort4*>(
                &smem[(16 * nj + l15) * ZSTR + 128 * w + 16 * ci + 4 * l4]) = o4;
        }
    __syncthreads();

    // ---- O phase: wave w owns o-rows [128w,+128) x all 64 n; wa dbuf
#pragma unroll
    for (int oi = 0; oi < 8; ++oi)
#pragma unroll
        for (int nj = 0; nj < 4; ++nj) acc[oi][nj] = (f32x4){0.f, 0.f, 0.f, 0.f};
    short8 wap[2][8];
#pragma unroll
    for (int oi = 0; oi < 8; ++oi)
        wap[0][oi] = ld8(&Wvb[(size_t)(128 * w + 16 * oi + l15) * CC + 8 * l4]);
#pragma unroll 2
    for (int ks = 0; ks < 16; ++ks) {
        const int cur = ks & 1;
        if (ks < 15) {
#pragma unroll
            for (int oi = 0; oi < 8; ++oi)
                wap[cur ^ 1][oi] = ld8(&Wvb[(size_t)(128 * w + 16 * oi + l15) * CC +
                                            32 * (ks + 1) + 8 * l4]);
        }
        short8 zb[4];
#pragma unroll
        for (int nj = 0; nj < 4; ++nj)
            zb[nj] = ld8(&smem[(16 * nj + l15) * ZSTR + 32 * ks + 8 * l4]);
        __builtin_amdgcn_s_setprio(1);
#pragma unroll
        for (int oi = 0; oi < 8; ++oi)
#pragma unroll
            for (int nj = 0; nj < 4; ++nj)
                acc[oi][nj] = MFMA16(zb[nj], wap[cur][oi], acc[oi][nj]);
        __builtin_amdgcn_s_setprio(0);
    }

    // ---- epilogue: float4 along n
    const float g = gamma[0];
#pragma unroll
    for (int oi = 0; oi < 8; ++oi) {
        int o = 128 * w + 16 * oi + l15;
        float bvo = bv[o];
#pragma unroll
        for (int nj = 0; nj < 4; ++nj) {
            int n = n0 + 16 * nj + 4 * l4;
            size_t idx = ((size_t)b * CC + o) * NN + n;
            float4 fc = *reinterpret_cast<const float4*>(&face[idx]);
            float4 ov;
            ov.x = g * (acc[oi][nj][0] + bvo) + fc.x;
            ov.y = g * (acc[oi][nj][1] + bvo) + fc.y;
            ov.z = g * (acc[oi][nj][2] + bvo) + fc.z;
            ov.w = g * (acc[oi][nj][3] + bvo) + fc.w;
            *reinterpret_cast<float4*>(&out[idx]) = ov;
        }
    }
#undef S_CHUNK
}

// ---------------------------------------------------------------------------
extern "C" void kernel_launch(void* const* d_in, const int* in_sizes, int n_in,
                              void* d_out, int out_size, void* d_ws, size_t ws_size,
                              hipStream_t stream) {
    const float* face  = (const float*)d_in[0];
    const float* audio = (const float*)d_in[1];
    const float* Wq    = (const float*)d_in[2];
    const float* bq    = (const float*)d_in[3];
    const float* Wk    = (const float*)d_in[4];
    const float* bk    = (const float*)d_in[5];
    const float* Wv    = (const float*)d_in[6];
    const float* bv    = (const float*)d_in[7];
    const float* gamma = (const float*)d_in[8];
    float* out = (float*)d_out;
    char* ws = (char*)d_ws;

    // workspace layout (bytes)
    ushort* Qt      = (ushort*)(ws + 0);                       // 4 MB
    ushort* Kt      = (ushort*)(ws + (4u << 20));              // 4 MB
    ushort* audio_b = (ushort*)(ws + (8u << 20));              // ~33 MB (padded)
    ushort* Wqb     = (ushort*)(ws + (44u << 20));             // 64 KB
    ushort* Wkb     = (ushort*)(ws + (44u << 20) + (64u << 10));
    ushort* Wvb     = (ushort*)(ws + (44u << 20) + (128u << 10));  // 512 KB

    hipLaunchKernelGGL(k_cvt3, dim3(320), dim3(256), 0, stream,
                       Wq, Wk, Wv, Wqb, Wkb, Wvb);
    hipLaunchKernelGGL(k_proj, dim3(16, 2, BB), dim3(256), 0, stream,
                       face, audio, Wqb, bq, Wkb, bk, Qt, Kt, audio_b);
    hipLaunchKernelGGL(k_attn, dim3(512), dim3(256), 0, stream,
                       Qt, Kt, audio_b, Wvb, bv, gamma, face, out);
}